// Round 8
// baseline (664.642 us; speedup 1.0000x reference)
//
#include <hip/hip_runtime.h>

typedef unsigned short u16;
typedef unsigned int   u32;
typedef float  f32x4  __attribute__((ext_vector_type(4)));
typedef float  fltx4  __attribute__((ext_vector_type(4)));
typedef float  f32x2  __attribute__((ext_vector_type(2)));
typedef short  bf16x8 __attribute__((ext_vector_type(8)));  // 8 bf16 bits in 4 VGPRs
typedef u32    u32x4  __attribute__((ext_vector_type(4)));
typedef u32    u32x2  __attribute__((ext_vector_type(2)));

#define CDIM 256
#define NPIX 4096
// (1/sqrt(256)) * log2(e): fold attention scale + exp2 conversion into wq3
#define QSCALE 0.09016843736f

__device__ __forceinline__ u16 f2bf(float f) {
  u32 u = __builtin_bit_cast(u32, f);
  u += 0x7fffu + ((u >> 16) & 1u);          // RNE truncate to bf16
  return (u16)(u >> 16);
}
__device__ __forceinline__ float bf2f(u16 h) {
  return __builtin_bit_cast(float, (u32)h << 16);
}

// raw v_exp_f32 (2^x, ~1 ULP). Identical to exp2f for |x| < 126; skips OCML guard.
#if __has_builtin(__builtin_amdgcn_exp2f)
#define FEXP2 __builtin_amdgcn_exp2f
#else
#define FEXP2 exp2f
#endif

#define LO2(v) __builtin_shufflevector(v, v, 0, 1)
#define HI2(v) __builtin_shufflevector(v, v, 2, 3)

union U8 { bf16x8 v; u16 u[8]; u32 w[4]; };

// async 16B/lane global->LDS DMA; lds_base is wave-uniform, HW adds lane*16
__device__ __forceinline__ void llds16(u16* lds_base, const u16* gsrc) {
  __builtin_amdgcn_global_load_lds(
      (const __attribute__((address_space(1))) unsigned int*)gsrc,
      (__attribute__((address_space(3))) unsigned int*)lds_base, 16, 0, 0);
}

// ----------------------------------------------- prep: weights->bf16 + wq3 partials
__global__ __launch_bounds__(256) void prep(const float* __restrict__ wkv,
                                            const float* __restrict__ wout,
                                            const float* __restrict__ wq,
                                            u16* __restrict__ w16,
                                            float* __restrict__ wq3p) {
  const int blk = blockIdx.x, tid = threadIdx.x;
  if (blk < 4) {
    const float* s = (blk < 2 ? wkv + 65536 : wout) + (blk & 1) * 32768;
    u16* d = w16 + (blk >> 1) * 65536 + (blk & 1) * 32768;
    for (int i = tid * 4; i < 32768; i += 1024) {
      fltx4 v = *(const fltx4*)(s + i);
      u32x2 o;
      o[0] = (u32)f2bf(v[0]) | ((u32)f2bf(v[1]) << 16);
      o[1] = (u32)f2bf(v[2]) | ((u32)f2bf(v[3]) << 16);
      *(u32x2*)(d + i) = o;
    }
  } else {
    const int p = blk - 4, c = tid;
    float a0 = 0.f, a1 = 0.f, a2 = 0.f;
    for (int o = p * 64; o < p * 64 + 64; ++o) {
      float kv = wkv[o * 256 + c];
      a0 += wq[o * 3 + 0] * kv;
      a1 += wq[o * 3 + 1] * kv;
      a2 += wq[o * 3 + 2] * kv;
    }
    float* dst = wq3p + (p * 256 + c) * 4;
    dst[0] = a0 * QSCALE; dst[1] = a1 * QSCALE; dst[2] = a2 * QSCALE; dst[3] = 0.f;
  }
}

// ---------------------------------------------------------------- groupnorm stats
__global__ __launch_bounds__(1024) void gn_stats(const float* __restrict__ x,
                                                 float* __restrict__ stats) {
  int bg = blockIdx.x;                       // b*32 + g ; group = 8 ch x 4096 contiguous
  const float* base = x + (long)bg * 32768;
  float s = 0.f, s2 = 0.f;
  for (int i = threadIdx.x; i < 8192; i += 1024) {
    fltx4 v = ((const fltx4*)base)[i];
    s  += v[0] + v[1] + v[2] + v[3];
    s2 += v[0]*v[0] + v[1]*v[1] + v[2]*v[2] + v[3]*v[3];
  }
  for (int off = 1; off < 64; off <<= 1) {
    s  += __shfl_xor(s, off);
    s2 += __shfl_xor(s2, off);
  }
  __shared__ float red[32];
  int w = threadIdx.x >> 6;                  // 16 waves
  if ((threadIdx.x & 63) == 0) { red[w] = s; red[16 + w] = s2; }
  __syncthreads();
  if (threadIdx.x < 16) {
    s  = red[threadIdx.x];
    s2 = red[16 + threadIdx.x];
    for (int off = 1; off < 16; off <<= 1) {
      s  += __shfl_xor(s, off);
      s2 += __shfl_xor(s2, off);
    }
    if (threadIdx.x == 0) {
      float mean = s * (1.f / 32768.f);
      float var  = s2 * (1.f / 32768.f) - mean * mean;
      stats[bg * 2]     = mean;
      stats[bg * 2 + 1] = rsqrtf(var + 1e-5f);
    }
  }
}

// --------------------- normalize + transpose -> normT[b][n][c] bf16, FUSED k3
__global__ __launch_bounds__(256) void gn_apply(const float* __restrict__ x,
                                                const float* __restrict__ stats,
                                                const float* __restrict__ gamma,
                                                const float* __restrict__ beta,
                                                const float* __restrict__ wq3p,
                                                u16* __restrict__ normT,
                                                float* __restrict__ K3x,
                                                float* __restrict__ K3y,
                                                float* __restrict__ K3z) {
  __shared__ u16 tile[256 * 66];             // 33 KB
  __shared__ float wl4[256 * 4];             // combined wq3, 4 KB
  __shared__ float part[4][64][4];           // c-quarter partial K3, 4 KB
  const int tid = threadIdx.x;
  const int b = blockIdx.y, nb = blockIdx.x * 64;
  const int nIn = tid & 63, c4 = tid >> 6;
  {
    const f32x4* wp = (const f32x4*)wq3p;
    *(f32x4*)&wl4[tid * 4] = wp[tid] + wp[256 + tid] + wp[512 + tid] + wp[768 + tid];
  }
  const float* xb = x + (long)b * (CDIM * NPIX);
  #pragma unroll 4
  for (int p = 0; p < 64; ++p) {
    int c = c4 * 64 + p;
    int g = c >> 3;
    float mean = stats[(b * 32 + g) * 2];
    float rstd = stats[(b * 32 + g) * 2 + 1];
    float v = xb[(long)c * NPIX + nb + nIn];
    tile[c * 66 + nIn] = f2bf((v - mean) * rstd * gamma[c] + beta[c]);
  }
  __syncthreads();
  u16* nT = normT + ((long)b * NPIX + nb) * CDIM;
  #pragma unroll 8
  for (int nl = 0; nl < 64; ++nl)
    nT[(long)nl * CDIM + tid] = tile[tid * 66 + nl];
  {
    float a0 = 0.f, a1 = 0.f, a2 = 0.f;
    #pragma unroll 8
    for (int cc = 0; cc < 64; ++cc) {
      int c = c4 * 64 + cc;
      float v = bf2f(tile[c * 66 + nIn]);
      const f32x4 wv = *(const f32x4*)&wl4[c * 4];
      a0 += v * wv[0]; a1 += v * wv[1]; a2 += v * wv[2];
    }
    part[c4][nIn][0] = a0; part[c4][nIn][1] = a1; part[c4][nIn][2] = a2;
  }
  __syncthreads();
  if (c4 == 0) {
    float s0 = part[0][nIn][0] + part[1][nIn][0] + part[2][nIn][0] + part[3][nIn][0];
    float s1 = part[0][nIn][1] + part[1][nIn][1] + part[2][nIn][1] + part[3][nIn][1];
    float s2 = part[0][nIn][2] + part[1][nIn][2] + part[2][nIn][2] + part[3][nIn][2];
    long idx = (long)b * NPIX + nb + nIn;
    K3x[idx] = s0; K3y[idx] = s1; K3z[idx] = s2;
  }
}

// ------------------------------------------------------------ generic NT GEMM, K=256
// WAYS=0: plain bf16 B. WAYS=2/4: B = (sum_w Opw) * 1/(sum_w ls[w*32768+n])
template <bool FINAL, int WAYS>
__global__ __launch_bounds__(256, 2) void gemm_nt(
    const void* __restrict__ Ap,
    const void* __restrict__ B0, const void* __restrict__ B1,
    const void* __restrict__ B2, const void* __restrict__ B3,
    const float* __restrict__ ls,
    void* __restrict__ Dp,
    const float* __restrict__ bias, const float* __restrict__ resid,
    int M, int N, long aBS, long bBS, long dBS, long rBS) {
  __shared__ u16 Als[128 * 72];
  __shared__ u16 Bls[128 * 72];
  __shared__ float invB[128];
  const int tid = threadIdx.x;
  const int lane = tid & 63;
  const int m = lane & 15, quad = lane >> 4;
  const int wid = tid >> 6;
  const int wm = wid & 1, wn = wid >> 1;
  const int m0 = blockIdx.x * 128, n0 = blockIdx.y * 128;
  const int bz = blockIdx.z;

  if constexpr (WAYS > 0) {
    if (tid < 128) {
      long n = (long)bz * 4096 + n0 + tid;
      float s = ls[n] + ls[32768 + n];
      if constexpr (WAYS == 4) s += ls[65536 + n] + ls[98304 + n];
      invB[tid] = 1.f / s;
    }
    __syncthreads();
  }

  f32x4 acc[4][4] = {};

  for (int ks = 0; ks < 4; ++ks) {
    const int kb = ks * 64;
    if (ks) __syncthreads();
    {
      const u16* src = (const u16*)Ap + aBS * bz;
      #pragma unroll
      for (int it = 0; it < 4; ++it) {
        int idx = it * 2048 + tid * 8;
        int r = idx >> 6, c = idx & 63;
        *(u32x4*)&Als[r * 72 + c] = *(const u32x4*)(src + (long)(m0 + r) * CDIM + kb + c);
      }
    }
    if constexpr (WAYS > 0) {
      const u16* s0 = (const u16*)B0 + bBS * bz;
      const u16* s1 = (const u16*)B1 + bBS * bz;
      const u16* s2 = (const u16*)B2 + bBS * bz;
      const u16* s3 = (const u16*)B3 + bBS * bz;
      #pragma unroll
      for (int it = 0; it < 4; ++it) {
        int idx = it * 2048 + tid * 8;
        int r = idx >> 6, c = idx & 63;
        long off = (long)(n0 + r) * CDIM + kb + c;
        u32x4 A0 = *(const u32x4*)(s0 + off);
        u32x4 A1 = *(const u32x4*)(s1 + off);
        u32x4 A2 = {}, A3 = {};
        if constexpr (WAYS == 4) {
          A2 = *(const u32x4*)(s2 + off);
          A3 = *(const u32x4*)(s3 + off);
        }
        float inv = invB[r];
        u32x4 o;
        #pragma unroll
        for (int i = 0; i < 4; ++i) {
          float lo = bf2f((u16)(A0[i] & 0xffff)) + bf2f((u16)(A1[i] & 0xffff));
          float hi = bf2f((u16)(A0[i] >> 16))    + bf2f((u16)(A1[i] >> 16));
          if constexpr (WAYS == 4) {
            lo += bf2f((u16)(A2[i] & 0xffff)) + bf2f((u16)(A3[i] & 0xffff));
            hi += bf2f((u16)(A2[i] >> 16))    + bf2f((u16)(A3[i] >> 16));
          }
          lo *= inv; hi *= inv;
          o[i] = (u32)f2bf(lo) | ((u32)f2bf(hi) << 16);
        }
        *(u32x4*)&Bls[r * 72 + c] = o;
      }
    } else {
      const u16* src = (const u16*)B0 + bBS * bz;
      #pragma unroll
      for (int it = 0; it < 4; ++it) {
        int idx = it * 2048 + tid * 8;
        int r = idx >> 6, c = idx & 63;
        *(u32x4*)&Bls[r * 72 + c] = *(const u32x4*)(src + (long)(n0 + r) * CDIM + kb + c);
      }
    }
    __syncthreads();
    #pragma unroll
    for (int s = 0; s < 2; ++s) {
      bf16x8 av[4], bv[4];
      #pragma unroll
      for (int i = 0; i < 4; ++i)
        av[i] = *(const bf16x8*)&Als[(wm * 64 + i * 16 + m) * 72 + s * 32 + quad * 8];
      #pragma unroll
      for (int i = 0; i < 4; ++i)
        bv[i] = *(const bf16x8*)&Bls[(wn * 64 + i * 16 + m) * 72 + s * 32 + quad * 8];
      #pragma unroll
      for (int mi = 0; mi < 4; ++mi)
        #pragma unroll
        for (int ni = 0; ni < 4; ++ni)
          acc[mi][ni] = __builtin_amdgcn_mfma_f32_16x16x32_bf16(av[mi], bv[ni], acc[mi][ni], 0, 0, 0);
    }
  }

  const int row0 = m0 + wm * 64;
  const int col0 = n0 + wn * 64 + m;
  if constexpr (FINAL) {
    float* out = (float*)Dp + dBS * bz;
    const float* res = resid + rBS * bz;
    #pragma unroll
    for (int mi = 0; mi < 4; ++mi)
      #pragma unroll
      for (int r = 0; r < 4; ++r) {
        int row = row0 + mi * 16 + quad * 4 + r;
        float bs = bias[row];
        #pragma unroll
        for (int ni = 0; ni < 4; ++ni) {
          long off = (long)row * N + col0 + ni * 16;
          out[off] = acc[mi][ni][r] + bs + res[off];
        }
      }
  } else {
    u16* out = (u16*)Dp + dBS * bz;
    #pragma unroll
    for (int mi = 0; mi < 4; ++mi)
      #pragma unroll
      for (int r = 0; r < 4; ++r) {
        int row = row0 + mi * 16 + quad * 4 + r;
        #pragma unroll
        for (int ni = 0; ni < 4; ++ni)
          out[(long)row * N + col0 + ni * 16] = f2bf(acc[mi][ni][r]);
      }
  }
}

// ------------------------------------------------------------------- flash attention
// R8: KVBLK=32, template NT = tiles/block (32 => 4-way split-K, 64 => 2-way).
// LDS 2x16KB dbuf => 4-way grid (32,4,8)=1024 blocks -> 4 blocks/CU, 4 waves/SIMD
// with LDS traffic per CU UNCHANGED vs R6 (4 waves x 16KB x 2x kt) and same
// 1-A-frag : 2-MFMA sharing (R7 lesson: occupancy must not scale waves x tile).
// Swizzle: 4 slots of 16B/row, XOR (c>>1)&3 (2-way banks = free), pre-swizzled
// on the GLOBAL side, LDS linear (DMA constraint).
#define MFMA16(a, bfr, c) __builtin_amdgcn_mfma_f32_16x16x32_bf16(a, bfr, c, 0, 0, 0)

#define PH_LOAD(h)                                                          \
  {                                                                         \
    const int jo_ = JB + quad * 8 + (h) * 4;                                \
    kxa = *(const fltx4*)(Kx + jo_);                                        \
    kya = *(const fltx4*)(Ky + jo_);                                        \
    kza = *(const fltx4*)(Kz + jo_);                                        \
  }

#define PH_EXP(PB, h)                                                       \
  {                                                                         \
    f32x2 xc0_ = LO2(kxa), xc1_ = HI2(kxa);                                 \
    f32x2 yc0_ = LO2(kya), yc1_ = HI2(kya);                                 \
    f32x2 zc0_ = LO2(kza), zc1_ = HI2(kza);                                 \
    _Pragma("unroll")                                                       \
    for (int qm_ = 0; qm_ < 2; ++qm_) {                                     \
      f32x2 s0_ = xc0_ * y2[qm_][0] + yc0_ * y2[qm_][1] + zc0_ * y2[qm_][2];\
      f32x2 s1_ = xc1_ * y2[qm_][0] + yc1_ * y2[qm_][1] + zc1_ * y2[qm_][2];\
      float p0_ = FEXP2(s0_[0]);                                            \
      float p1_ = FEXP2(s0_[1]);                                            \
      float p2_ = FEXP2(s1_[0]);                                            \
      float p3_ = FEXP2(s1_[1]);                                            \
      u32 r0_ = __builtin_bit_cast(u32, p0_) + 0x8000u;                     \
      u32 r1_ = __builtin_bit_cast(u32, p1_) + 0x8000u;                     \
      u32 r2_ = __builtin_bit_cast(u32, p2_) + 0x8000u;                     \
      u32 r3_ = __builtin_bit_cast(u32, p3_) + 0x8000u;                     \
      PB[qm_].w[(h) * 2]     = (r0_ >> 16) | (r1_ & 0xffff0000u);           \
      PB[qm_].w[(h) * 2 + 1] = (r2_ >> 16) | (r3_ & 0xffff0000u);           \
      f32x2 pa_; pa_[0] = p0_; pa_[1] = p1_;                                \
      f32x2 pc_; pc_[0] = p2_; pc_[1] = p3_;                                \
      lsv[qm_] += pa_ + pc_;                                                \
    }                                                                       \
  }

#define PV_G(PB, CT0)                                                       \
  _Pragma("unroll")                                                         \
  for (int ct_ = (CT0); ct_ < (CT0) + 4; ++ct_) {                           \
    int c_ = ct_ * 16 + m;                                                  \
    bf16x8 a_ = *(const bf16x8*)&Vb[c_ * 32 + ((quad ^ ((c_ >> 1) & 3)) << 3)]; \
    acc[0][ct_] = MFMA16(a_, PB[0].v, acc[0][ct_]);                         \
    acc[1][ct_] = MFMA16(a_, PB[1].v, acc[1][ct_]);                         \
  }

template <int NT>   // tiles of 32 keys per block
__global__ __launch_bounds__(256, 4) void attn_kernel(
    const float* __restrict__ quary,
    const float* __restrict__ K3x, const float* __restrict__ K3y,
    const float* __restrict__ K3z,
    const u16* __restrict__ V,
    u16* __restrict__ Op0, u16* __restrict__ Op1,
    u16* __restrict__ Op2, u16* __restrict__ Op3,
    float* __restrict__ lsum) {
  __shared__ u16 VLS[2][256 * 32];   // 2 x 16 KB; row c x 32 keys, slot ^= (c>>1)&3
  const int lane = threadIdx.x & 63, w = threadIdx.x >> 6;   // w in [0,4)
  const int m = lane & 15, quad = lane >> 4;
  const int b = blockIdx.z, way = blockIdx.y;
  const int qb = blockIdx.x * 128 + w * 32;                  // 32 q per wave
  const int kv0 = way * (NT * 32);

  // per-lane query channel splats, both q-tiles
  f32x2 y2[2][3];
  #pragma unroll
  for (int qm = 0; qm < 2; ++qm) {
    int n = qb + qm * 16 + m;
    float q0 = quary[b * 12288 + n];
    float q1 = quary[b * 12288 + 4096 + n];
    float q2 = quary[b * 12288 + 8192 + n];
    y2[qm][0][0] = q0; y2[qm][0][1] = q0;
    y2[qm][1][0] = q1; y2[qm][1][1] = q1;
    y2[qm][2][0] = q2; y2[qm][2][1] = q2;
  }

  const float* Kx = K3x + (long)b * NPIX + kv0;
  const float* Ky = K3y + (long)b * NPIX + kv0;
  const float* Kz = K3z + (long)b * NPIX + kv0;
  const u16* VG = V + (long)b * CDIM * NPIX + kv0;

  // staging: 4 waves x 4 chunks (1 KB); chunk = 16 c-rows x 32 keys.
  // lane l: c = chunk*16 + (l>>2), slot s = l&3; global key-slot = s ^ ((c>>1)&3)
  int srcV[4];
  #pragma unroll
  for (int i = 0; i < 4; ++i) {
    int c = (w * 4 + i) * 16 + (lane >> 2);
    int s = lane & 3;
    srcV[i] = c * NPIX + ((s ^ ((c >> 1) & 3)) << 3);
  }

  f32x2 lsv[2] = {};
  f32x4 acc[2][16] = {};
  U8 pbA[2], pbB[2];
  fltx4 kxa, kya, kza;

  // prime buffer 0 with tile 0
  #pragma unroll
  for (int i = 0; i < 4; ++i)
    llds16(VLS[0] + (w * 4 + i) * 512, VG + srcV[i]);

  // P(tile 0) while the priming DMA is in flight
  {
    const int JB = 0;
    PH_LOAD(0); PH_EXP(pbA, 0);
    PH_LOAD(1); PH_EXP(pbA, 1);
  }

  for (int kt = 0; kt < NT - 1; ++kt) {
    __syncthreads();   // own DMA drained (vmcnt) -> tile kt ready; prev reads done
    #pragma unroll
    for (int i = 0; i < 4; ++i)
      llds16(VLS[(kt + 1) & 1] + (w * 4 + i) * 512, VG + srcV[i] + (kt + 1) * 32);
    const u16* Vb = VLS[kt & 1];
    const int JB = (kt + 1) * 32;

    PH_LOAD(0);                         // K3 loads issue; latency hides under PV
    PV_G(pbA, 0);
    PV_G(pbA, 4);
    PH_EXP(pbB, 0);
    PH_LOAD(1);
    PV_G(pbA, 8);
    PV_G(pbA, 12);
    PH_EXP(pbB, 1);

    pbA[0] = pbB[0]; pbA[1] = pbB[1];
  }
  {  // epilogue: last tile, no further P / prefetch
    __syncthreads();
    const u16* Vb = VLS[(NT - 1) & 1];
    PV_G(pbA, 0);
    PV_G(pbA, 4);
    PV_G(pbA, 8);
    PV_G(pbA, 12);
  }

  // ---- store UNNORMALIZED partial O (bf16) + per-row l
  u16* OpB = (way == 0) ? Op0 : (way == 1) ? Op1 : (way == 2) ? Op2 : Op3;
  #pragma unroll
  for (int qm = 0; qm < 2; ++qm) {
    int n = qb + qm * 16 + m;
    u16* row = OpB + ((long)b * NPIX + n) * CDIM + quad * 4;  // D: col=n, row=quad*4+r
    #pragma unroll
    for (int ct = 0; ct < 16; ++ct) {
      u32x2 o;
      o[0] = (u32)f2bf(acc[qm][ct][0]) | ((u32)f2bf(acc[qm][ct][1]) << 16);
      o[1] = (u32)f2bf(acc[qm][ct][2]) | ((u32)f2bf(acc[qm][ct][3]) << 16);
      *(u32x2*)(row + ct * 16) = o;
    }
    float ls = lsv[qm][0] + lsv[qm][1];
    ls += __shfl_xor(ls, 16);
    ls += __shfl_xor(ls, 32);
    if (lane < 16)
      lsum[(long)way * 32768 + (long)b * NPIX + n] = ls;
  }
}

// ----------------------------------------------------------------------- launch
extern "C" void kernel_launch(void* const* d_in, const int* in_sizes, int n_in,
                              void* d_out, int out_size, void* d_ws, size_t ws_size,
                              hipStream_t stream) {
  (void)in_sizes; (void)n_in; (void)out_size;
  const float* input = (const float*)d_in[0];   // (8,256,64,64)
  const float* quary = (const float*)d_in[1];   // (8,3,64,64)
  const float* gnw   = (const float*)d_in[2];   // (256)
  const float* gnb   = (const float*)d_in[3];   // (256)
  const float* wq    = (const float*)d_in[4];   // (256,3)
  const float* wkv   = (const float*)d_in[5];   // (512,256)
  const float* wout  = (const float*)d_in[6];   // (256,256)
  const float* bout  = (const float*)d_in[7];   // (256)
  float* out = (float*)d_out;

  char* ws = (char*)d_ws;
  float* stats = (float*)ws;                              // 4 KB    @0
  float* wq3p  = (float*)(ws + 4096);                     // 16 KB
  float* lsum  = (float*)(ws + 20480);                    // 512 KB (4 x 32768 f32)
  float* K3x   = (float*)(ws + 544768);                   // 128 KB plane
  float* K3y   = (float*)(ws + 675840);                   // 128 KB plane
  float* K3z   = (float*)(ws + 806912);                   // 128 KB plane
  u16* w16   = (u16*)(ws + 937984);                       // 256 KB -> ends 1200128
  const long base = 1200128;
  u16* normT = (u16*)(ws + base);                         // 16 MiB; dead after gemmV
  u16* Vv    = (u16*)(ws + base + 1L * 16777216);         // 16 MiB (B,C,N)
  u16* Op0   = normT;                                     // reuse dead region
  u16* Op1   = (u16*)(ws + base + 2L * 16777216);
  u16* Op2   = (u16*)(ws + base + 3L * 16777216);
  u16* Op3   = (u16*)(ws + base + 4L * 16777216);
  const size_t need4 = (size_t)base + 5ul * 16777216ul;
  const int ways = (ws_size >= need4) ? 4 : 2;

  const long S = (long)NPIX * CDIM;                       // 1048576 per-batch stride

  prep<<<8, 256, 0, stream>>>(wkv, wout, wq, w16, wq3p);
  gn_stats<<<256, 1024, 0, stream>>>(input, stats);
  gn_apply<<<dim3(64, 8), 256, 0, stream>>>(input, stats, gnw, gnb, wq3p,
                                            normT, K3x, K3y, K3z);
  // V[o][n] = sum_c wkvV16[o][c] * normT[n][c]
  gemm_nt<false, 0><<<dim3(2, 32, 8), 256, 0, stream>>>(
      w16, normT, nullptr, nullptr, nullptr, nullptr, Vv, nullptr, nullptr,
      256, 4096, 0, S, S, 0);
  if (ways == 4) {
    attn_kernel<32><<<dim3(32, 4, 8), 256, 0, stream>>>(
        quary, K3x, K3y, K3z, Vv, Op0, Op1, Op2, Op3, lsum);
    gemm_nt<true, 4><<<dim3(2, 32, 8), 256, 0, stream>>>(
        w16 + 65536, Op0, Op1, Op2, Op3, lsum, out, bout, input,
        256, 4096, 0, S, S, S);
  } else {
    attn_kernel<64><<<dim3(32, 2, 8), 256, 0, stream>>>(
        quary, K3x, K3y, K3z, Vv, Op0, Op1, Op2, Op3, lsum);
    gemm_nt<true, 2><<<dim3(2, 32, 8), 256, 0, stream>>>(
        w16 + 65536, Op0, Op1, Op2, Op3, lsum, out, bout, input,
        256, 4096, 0, S, S, S);
  }
}

// Round 9
// 233.062 us; speedup vs baseline: 2.8518x; 2.8518x over previous
//
#include <hip/hip_runtime.h>

typedef unsigned short u16;
typedef unsigned int   u32;
typedef float  f32x4  __attribute__((ext_vector_type(4)));
typedef float  fltx4  __attribute__((ext_vector_type(4)));
typedef float  f32x2  __attribute__((ext_vector_type(2)));
typedef short  bf16x8 __attribute__((ext_vector_type(8)));  // 8 bf16 bits in 4 VGPRs
typedef u32    u32x4  __attribute__((ext_vector_type(4)));
typedef u32    u32x2  __attribute__((ext_vector_type(2)));

#define CDIM 256
#define NPIX 4096
// (1/sqrt(256)) * log2(e): fold attention scale + exp2 conversion into wq3
#define QSCALE 0.09016843736f

__device__ __forceinline__ u16 f2bf(float f) {
  u32 u = __builtin_bit_cast(u32, f);
  u += 0x7fffu + ((u >> 16) & 1u);          // RNE truncate to bf16
  return (u16)(u >> 16);
}
__device__ __forceinline__ float bf2f(u16 h) {
  return __builtin_bit_cast(float, (u32)h << 16);
}

// raw v_exp_f32 (2^x, ~1 ULP). Identical to exp2f for |x| < 126; skips OCML guard.
#if __has_builtin(__builtin_amdgcn_exp2f)
#define FEXP2 __builtin_amdgcn_exp2f
#else
#define FEXP2 exp2f
#endif

#define LO2(v) __builtin_shufflevector(v, v, 0, 1)
#define HI2(v) __builtin_shufflevector(v, v, 2, 3)

union U8 { bf16x8 v; u16 u[8]; u32 w[4]; };

// async 16B/lane global->LDS DMA; lds_base is wave-uniform, HW adds lane*16
__device__ __forceinline__ void llds16(u16* lds_base, const u16* gsrc) {
  __builtin_amdgcn_global_load_lds(
      (const __attribute__((address_space(1))) unsigned int*)gsrc,
      (__attribute__((address_space(3))) unsigned int*)lds_base, 16, 0, 0);
}

// ----------------------------------------------- prep: weights->bf16 + wq3 partials
__global__ __launch_bounds__(256) void prep(const float* __restrict__ wkv,
                                            const float* __restrict__ wout,
                                            const float* __restrict__ wq,
                                            u16* __restrict__ w16,
                                            float* __restrict__ wq3p) {
  const int blk = blockIdx.x, tid = threadIdx.x;
  if (blk < 4) {
    const float* s = (blk < 2 ? wkv + 65536 : wout) + (blk & 1) * 32768;
    u16* d = w16 + (blk >> 1) * 65536 + (blk & 1) * 32768;
    for (int i = tid * 4; i < 32768; i += 1024) {
      fltx4 v = *(const fltx4*)(s + i);
      u32x2 o;
      o[0] = (u32)f2bf(v[0]) | ((u32)f2bf(v[1]) << 16);
      o[1] = (u32)f2bf(v[2]) | ((u32)f2bf(v[3]) << 16);
      *(u32x2*)(d + i) = o;
    }
  } else {
    const int p = blk - 4, c = tid;
    float a0 = 0.f, a1 = 0.f, a2 = 0.f;
    for (int o = p * 64; o < p * 64 + 64; ++o) {
      float kv = wkv[o * 256 + c];
      a0 += wq[o * 3 + 0] * kv;
      a1 += wq[o * 3 + 1] * kv;
      a2 += wq[o * 3 + 2] * kv;
    }
    float* dst = wq3p + (p * 256 + c) * 4;
    dst[0] = a0 * QSCALE; dst[1] = a1 * QSCALE; dst[2] = a2 * QSCALE; dst[3] = 0.f;
  }
}

// ---------------------------------------------------------------- groupnorm stats
__global__ __launch_bounds__(1024) void gn_stats(const float* __restrict__ x,
                                                 float* __restrict__ stats) {
  int bg = blockIdx.x;                       // b*32 + g ; group = 8 ch x 4096 contiguous
  const float* base = x + (long)bg * 32768;
  float s = 0.f, s2 = 0.f;
  for (int i = threadIdx.x; i < 8192; i += 1024) {
    fltx4 v = ((const fltx4*)base)[i];
    s  += v[0] + v[1] + v[2] + v[3];
    s2 += v[0]*v[0] + v[1]*v[1] + v[2]*v[2] + v[3]*v[3];
  }
  for (int off = 1; off < 64; off <<= 1) {
    s  += __shfl_xor(s, off);
    s2 += __shfl_xor(s2, off);
  }
  __shared__ float red[32];
  int w = threadIdx.x >> 6;                  // 16 waves
  if ((threadIdx.x & 63) == 0) { red[w] = s; red[16 + w] = s2; }
  __syncthreads();
  if (threadIdx.x < 16) {
    s  = red[threadIdx.x];
    s2 = red[16 + threadIdx.x];
    for (int off = 1; off < 16; off <<= 1) {
      s  += __shfl_xor(s, off);
      s2 += __shfl_xor(s2, off);
    }
    if (threadIdx.x == 0) {
      float mean = s * (1.f / 32768.f);
      float var  = s2 * (1.f / 32768.f) - mean * mean;
      stats[bg * 2]     = mean;
      stats[bg * 2 + 1] = rsqrtf(var + 1e-5f);
    }
  }
}

// --------------------- FUSED: groupnorm-apply + K3 + V-GEMM (normT eliminated)
// Block = 64 n x 256 c. Tile stored [n][c] bf16 (stride 264: 16B-aligned rows,
// 2-way-bank LDS). Phase 1: normalize -> tile. Phase 2: K3 via bf16x8 row reads.
// Phase 3: V[o][n] = sum_c w16V[o][c] * tile[n][c] via MFMA (A from L2, B from
// LDS) -> Vv. Removes 16MB normT write + 16MB read + one dispatch.
#define TSTR 264
__global__ __launch_bounds__(256) void gn_fused(const float* __restrict__ x,
                                                const float* __restrict__ stats,
                                                const float* __restrict__ gamma,
                                                const float* __restrict__ beta,
                                                const float* __restrict__ wq3p,
                                                const u16* __restrict__ w16v,
                                                u16* __restrict__ Vv,
                                                float* __restrict__ K3x,
                                                float* __restrict__ K3y,
                                                float* __restrict__ K3z) {
  __shared__ u16 tile[64 * TSTR];            // ~33.8 KB, [n][c]
  __shared__ float wl4[256 * 4];             // combined wq3, 4 KB
  __shared__ float part[4][64][4];           // c-quarter partial K3, 4 KB
  const int tid = threadIdx.x;
  const int b = blockIdx.y, nb = blockIdx.x * 64;
  const int nIn = tid & 63, c4 = tid >> 6;   // c4 = wave
  const int lane = tid & 63;
  const int m = lane & 15, quad = lane >> 4;
  {
    const f32x4* wp = (const f32x4*)wq3p;
    *(f32x4*)&wl4[tid * 4] = wp[tid] + wp[256 + tid] + wp[512 + tid] + wp[768 + tid];
  }
  const float* xb = x + (long)b * (CDIM * NPIX);
  // ---- phase 1: normalize 64 c-rows (this wave's quarter) for column nIn
  #pragma unroll
  for (int p8 = 0; p8 < 8; ++p8) {
    U8 pk;
    #pragma unroll
    for (int e = 0; e < 8; ++e) {
      int c = c4 * 64 + p8 * 8 + e;
      int g = c >> 3;
      float mean = stats[(b * 32 + g) * 2];
      float rstd = stats[(b * 32 + g) * 2 + 1];
      float v = xb[(long)c * NPIX + nb + nIn];
      pk.u[e] = f2bf((v - mean) * rstd * gamma[c] + beta[c]);
    }
    *(bf16x8*)&tile[nIn * TSTR + c4 * 64 + p8 * 8] = pk.v;
  }
  __syncthreads();
  // ---- phase 2: K3 partial, vectorized row reads
  {
    float a0 = 0.f, a1 = 0.f, a2 = 0.f;
    #pragma unroll
    for (int p8 = 0; p8 < 8; ++p8) {
      U8 v; v.v = *(const bf16x8*)&tile[nIn * TSTR + c4 * 64 + p8 * 8];
      #pragma unroll
      for (int e = 0; e < 8; ++e) {
        int c = c4 * 64 + p8 * 8 + e;
        float f = bf2f(v.u[e]);
        const f32x4 wv = *(const f32x4*)&wl4[c * 4];
        a0 += f * wv[0]; a1 += f * wv[1]; a2 += f * wv[2];
      }
    }
    part[c4][nIn][0] = a0; part[c4][nIn][1] = a1; part[c4][nIn][2] = a2;
  }
  __syncthreads();
  if (c4 == 0) {
    float s0 = part[0][nIn][0] + part[1][nIn][0] + part[2][nIn][0] + part[3][nIn][0];
    float s1 = part[0][nIn][1] + part[1][nIn][1] + part[2][nIn][1] + part[3][nIn][1];
    float s2 = part[0][nIn][2] + part[1][nIn][2] + part[2][nIn][2] + part[3][nIn][2];
    long idx = (long)b * NPIX + nb + nIn;
    K3x[idx] = s0; K3y[idx] = s1; K3z[idx] = s2;
  }
  // ---- phase 3: V-GEMM. wave c4 owns o-range [c4*64, c4*64+64).
  f32x4 acc[4][4] = {};
  #pragma unroll
  for (int ks = 0; ks < 8; ++ks) {
    const int kb = ks * 32;
    bf16x8 av[4], bv[4];
    #pragma unroll
    for (int i = 0; i < 4; ++i)
      av[i] = *(const bf16x8*)&w16v[(c4 * 64 + i * 16 + m) * 256 + kb + quad * 8];
    #pragma unroll
    for (int i = 0; i < 4; ++i)
      bv[i] = *(const bf16x8*)&tile[(i * 16 + m) * TSTR + kb + quad * 8];
    #pragma unroll
    for (int mi = 0; mi < 4; ++mi)
      #pragma unroll
      for (int ni = 0; ni < 4; ++ni)
        acc[mi][ni] = __builtin_amdgcn_mfma_f32_16x16x32_bf16(av[mi], bv[ni], acc[mi][ni], 0, 0, 0);
  }
  u16* Vb = Vv + (long)b * (CDIM * NPIX);
  #pragma unroll
  for (int mi = 0; mi < 4; ++mi)
    #pragma unroll
    for (int r = 0; r < 4; ++r) {
      int o = c4 * 64 + mi * 16 + quad * 4 + r;
      #pragma unroll
      for (int ni = 0; ni < 4; ++ni)
        Vb[(long)o * NPIX + nb + ni * 16 + m] = f2bf(acc[mi][ni][r]);
    }
}

// ------------------------------------------------------------ generic NT GEMM, K=256
// WAYS=0: plain bf16 B. WAYS=2: B = (B0+B1) * 1/(ls[n]+ls[32768+n])
template <bool FINAL, int WAYS>
__global__ __launch_bounds__(256, 2) void gemm_nt(
    const void* __restrict__ Ap,
    const void* __restrict__ B0, const void* __restrict__ B1,
    const float* __restrict__ ls,
    void* __restrict__ Dp,
    const float* __restrict__ bias, const float* __restrict__ resid,
    int M, int N, long aBS, long bBS, long dBS, long rBS) {
  __shared__ u16 Als[128 * 72];
  __shared__ u16 Bls[128 * 72];
  __shared__ float invB[128];
  const int tid = threadIdx.x;
  const int lane = tid & 63;
  const int m = lane & 15, quad = lane >> 4;
  const int wid = tid >> 6;
  const int wm = wid & 1, wn = wid >> 1;
  const int m0 = blockIdx.x * 128, n0 = blockIdx.y * 128;
  const int bz = blockIdx.z;

  if constexpr (WAYS > 0) {
    if (tid < 128) {
      long n = (long)bz * 4096 + n0 + tid;
      invB[tid] = 1.f / (ls[n] + ls[32768 + n]);
    }
    __syncthreads();
  }

  f32x4 acc[4][4] = {};

  for (int ks = 0; ks < 4; ++ks) {
    const int kb = ks * 64;
    if (ks) __syncthreads();
    {
      const u16* src = (const u16*)Ap + aBS * bz;
      #pragma unroll
      for (int it = 0; it < 4; ++it) {
        int idx = it * 2048 + tid * 8;
        int r = idx >> 6, c = idx & 63;
        *(u32x4*)&Als[r * 72 + c] = *(const u32x4*)(src + (long)(m0 + r) * CDIM + kb + c);
      }
    }
    if constexpr (WAYS > 0) {
      const u16* s0 = (const u16*)B0 + bBS * bz;
      const u16* s1 = (const u16*)B1 + bBS * bz;
      #pragma unroll
      for (int it = 0; it < 4; ++it) {
        int idx = it * 2048 + tid * 8;
        int r = idx >> 6, c = idx & 63;
        long off = (long)(n0 + r) * CDIM + kb + c;
        u32x4 A0 = *(const u32x4*)(s0 + off);
        u32x4 A1 = *(const u32x4*)(s1 + off);
        float inv = invB[r];
        u32x4 o;
        #pragma unroll
        for (int i = 0; i < 4; ++i) {
          float lo = (bf2f((u16)(A0[i] & 0xffff)) + bf2f((u16)(A1[i] & 0xffff))) * inv;
          float hi = (bf2f((u16)(A0[i] >> 16))    + bf2f((u16)(A1[i] >> 16)))    * inv;
          o[i] = (u32)f2bf(lo) | ((u32)f2bf(hi) << 16);
        }
        *(u32x4*)&Bls[r * 72 + c] = o;
      }
    } else {
      const u16* src = (const u16*)B0 + bBS * bz;
      #pragma unroll
      for (int it = 0; it < 4; ++it) {
        int idx = it * 2048 + tid * 8;
        int r = idx >> 6, c = idx & 63;
        *(u32x4*)&Bls[r * 72 + c] = *(const u32x4*)(src + (long)(n0 + r) * CDIM + kb + c);
      }
    }
    __syncthreads();
    #pragma unroll
    for (int s = 0; s < 2; ++s) {
      bf16x8 av[4], bv[4];
      #pragma unroll
      for (int i = 0; i < 4; ++i)
        av[i] = *(const bf16x8*)&Als[(wm * 64 + i * 16 + m) * 72 + s * 32 + quad * 8];
      #pragma unroll
      for (int i = 0; i < 4; ++i)
        bv[i] = *(const bf16x8*)&Bls[(wn * 64 + i * 16 + m) * 72 + s * 32 + quad * 8];
      #pragma unroll
      for (int mi = 0; mi < 4; ++mi)
        #pragma unroll
        for (int ni = 0; ni < 4; ++ni)
          acc[mi][ni] = __builtin_amdgcn_mfma_f32_16x16x32_bf16(av[mi], bv[ni], acc[mi][ni], 0, 0, 0);
    }
  }

  const int row0 = m0 + wm * 64;
  const int col0 = n0 + wn * 64 + m;
  if constexpr (FINAL) {
    float* out = (float*)Dp + dBS * bz;
    const float* res = resid + rBS * bz;
    #pragma unroll
    for (int mi = 0; mi < 4; ++mi)
      #pragma unroll
      for (int r = 0; r < 4; ++r) {
        int row = row0 + mi * 16 + quad * 4 + r;
        float bs = bias[row];
        #pragma unroll
        for (int ni = 0; ni < 4; ++ni) {
          long off = (long)row * N + col0 + ni * 16;
          out[off] = acc[mi][ni][r] + bs + res[off];
        }
      }
  } else {
    u16* out = (u16*)Dp + dBS * bz;
    #pragma unroll
    for (int mi = 0; mi < 4; ++mi)
      #pragma unroll
      for (int r = 0; r < 4; ++r) {
        int row = row0 + mi * 16 + quad * 4 + r;
        #pragma unroll
        for (int ni = 0; ni < 4; ++ni)
          out[(long)row * N + col0 + ni * 16] = f2bf(acc[mi][ni][r]);
      }
  }
}

// ------------------------------------------------------------------- flash attention
// VERBATIM R6 structure (banked 98.5us): KVBLK=64, 2-way split-K, 4 waves x 32 q,
// rolled pipeline, FEXP2, LDS 64KB dbuf, 2 blocks/CU. (R7: 16q/wave doubled LDS
// traffic -> LDS-bound. R8: launch_bounds(,4) with 128-reg acc -> scratch spill.)
#define MFMA16(a, bfr, c) __builtin_amdgcn_mfma_f32_16x16x32_bf16(a, bfr, c, 0, 0, 0)

#define P_LOAD(ks, JB)                                                      \
  {                                                                         \
    const int jo_ = (JB) + (ks) * 32 + quad * 8;                            \
    kx0 = *(const fltx4*)(Kx + jo_); kx1 = *(const fltx4*)(Kx + jo_ + 4);   \
    ky0 = *(const fltx4*)(Ky + jo_); ky1 = *(const fltx4*)(Ky + jo_ + 4);   \
    kz0 = *(const fltx4*)(Kz + jo_); kz1 = *(const fltx4*)(Kz + jo_ + 4);   \
  }

#define P_EXP(PB, ks)                                                       \
  {                                                                         \
    f32x2 xc_[4] = {LO2(kx0), HI2(kx0), LO2(kx1), HI2(kx1)};                \
    f32x2 yc_[4] = {LO2(ky0), HI2(ky0), LO2(ky1), HI2(ky1)};                \
    f32x2 zc_[4] = {LO2(kz0), HI2(kz0), LO2(kz1), HI2(kz1)};                \
    _Pragma("unroll")                                                       \
    for (int qm_ = 0; qm_ < 2; ++qm_) {                                     \
      _Pragma("unroll")                                                     \
      for (int c2_ = 0; c2_ < 4; ++c2_) {                                   \
        f32x2 s_ = xc_[c2_] * y2[qm_][0] + yc_[c2_] * y2[qm_][1]            \
                 + zc_[c2_] * y2[qm_][2];                                   \
        float p0_ = FEXP2(s_[0]);                                           \
        float p1_ = FEXP2(s_[1]);                                           \
        u32 r0_ = __builtin_bit_cast(u32, p0_) + 0x8000u;                   \
        u32 r1_ = __builtin_bit_cast(u32, p1_) + 0x8000u;                   \
        PB[qm_][ks].w[c2_] = (r0_ >> 16) | (r1_ & 0xffff0000u);             \
        f32x2 pv_; pv_[0] = p0_; pv_[1] = p1_;                              \
        lsv[qm_] += pv_;                                                    \
      }                                                                     \
    }                                                                       \
  }

#define PV_GROUP(PB, CT0)                                                   \
  _Pragma("unroll")                                                         \
  for (int ct_ = (CT0); ct_ < (CT0) + 4; ++ct_) {                           \
    int c_ = ct_ * 16 + m;                                                  \
    bf16x8 a0_ = *(const bf16x8*)&Vb[c_ * 64 + (((quad)     ^ (c_ & 7)) << 3)]; \
    bf16x8 a1_ = *(const bf16x8*)&Vb[c_ * 64 + (((4 + quad) ^ (c_ & 7)) << 3)]; \
    acc[0][ct_] = MFMA16(a0_, PB[0][0].v, acc[0][ct_]);                     \
    acc[1][ct_] = MFMA16(a0_, PB[1][0].v, acc[1][ct_]);                     \
    acc[0][ct_] = MFMA16(a1_, PB[0][1].v, acc[0][ct_]);                     \
    acc[1][ct_] = MFMA16(a1_, PB[1][1].v, acc[1][ct_]);                     \
  }

__global__ __launch_bounds__(256, 2) void attn_kernel(
    const float* __restrict__ quary,
    const float* __restrict__ K3x, const float* __restrict__ K3y,
    const float* __restrict__ K3z,
    const u16* __restrict__ V, u16* __restrict__ Op0, u16* __restrict__ Op1,
    float* __restrict__ lsum) {
  __shared__ u16 VLS[2][256 * 64];   // 2 x 32 KB; row c (256) x 64 keys, chunk ^= (c&7)
  const int lane = threadIdx.x & 63, w = threadIdx.x >> 6;   // w in [0,4)
  const int m = lane & 15, quad = lane >> 4;
  const int b = blockIdx.z, half = blockIdx.y;
  const int qb = blockIdx.x * 128 + w * 32;                  // 32 q per wave

  f32x2 y2[2][3];
  #pragma unroll
  for (int qm = 0; qm < 2; ++qm) {
    int n = qb + qm * 16 + m;
    float q0 = quary[b * 12288 + n];
    float q1 = quary[b * 12288 + 4096 + n];
    float q2 = quary[b * 12288 + 8192 + n];
    y2[qm][0][0] = q0; y2[qm][0][1] = q0;
    y2[qm][1][0] = q1; y2[qm][1][1] = q1;
    y2[qm][2][0] = q2; y2[qm][2][1] = q2;
  }

  const float* Kx = K3x + (long)b * NPIX + half * 2048;
  const float* Ky = K3y + (long)b * NPIX + half * 2048;
  const float* Kz = K3z + (long)b * NPIX + half * 2048;
  const u16* VG = V + (long)b * CDIM * NPIX + half * 2048;

  int srcV[8];
  #pragma unroll
  for (int i = 0; i < 8; ++i) {
    int c = (w * 8 + i) * 8 + (lane >> 3);
    srcV[i] = c * NPIX + (((lane & 7) ^ (c & 7)) << 3);
  }

  f32x2 lsv[2] = {};
  f32x4 acc[2][16] = {};
  U8 pbA[2][2], pbB[2][2];
  fltx4 kx0, kx1, ky0, ky1, kz0, kz1;

  #pragma unroll
  for (int i = 0; i < 8; ++i)
    llds16(VLS[0] + (w * 8 + i) * 512, VG + srcV[i]);

  P_LOAD(0, 0); P_EXP(pbA, 0);
  P_LOAD(1, 0); P_EXP(pbA, 1);

  for (int kt = 0; kt < 31; ++kt) {
    __syncthreads();
    #pragma unroll
    for (int i = 0; i < 8; ++i)
      llds16(VLS[(kt + 1) & 1] + (w * 8 + i) * 512, VG + srcV[i] + (kt + 1) * 64);
    const u16* Vb = VLS[kt & 1];
    const int JB = (kt + 1) * 64;

    P_LOAD(0, JB);
    PV_GROUP(pbA, 0);
    PV_GROUP(pbA, 4);
    P_EXP(pbB, 0);
    P_LOAD(1, JB);
    PV_GROUP(pbA, 8);
    PV_GROUP(pbA, 12);
    P_EXP(pbB, 1);

    pbA[0][0] = pbB[0][0]; pbA[0][1] = pbB[0][1];
    pbA[1][0] = pbB[1][0]; pbA[1][1] = pbB[1][1];
  }
  {
    __syncthreads();
    const u16* Vb = VLS[1];
    PV_GROUP(pbA, 0);
    PV_GROUP(pbA, 4);
    PV_GROUP(pbA, 8);
    PV_GROUP(pbA, 12);
  }

  u16* OpB = (half ? Op1 : Op0);
  #pragma unroll
  for (int qm = 0; qm < 2; ++qm) {
    int n = qb + qm * 16 + m;
    u16* row = OpB + ((long)b * NPIX + n) * CDIM + quad * 4;
    #pragma unroll
    for (int ct = 0; ct < 16; ++ct) {
      u32x2 o;
      o[0] = (u32)f2bf(acc[qm][ct][0]) | ((u32)f2bf(acc[qm][ct][1]) << 16);
      o[1] = (u32)f2bf(acc[qm][ct][2]) | ((u32)f2bf(acc[qm][ct][3]) << 16);
      *(u32x2*)(row + ct * 16) = o;
    }
    float ls = lsv[qm][0] + lsv[qm][1];
    ls += __shfl_xor(ls, 16);
    ls += __shfl_xor(ls, 32);
    if (lane < 16)
      lsum[(long)half * 32768 + (long)b * NPIX + n] = ls;
  }
}

// ----------------------------------------------------------------------- launch
extern "C" void kernel_launch(void* const* d_in, const int* in_sizes, int n_in,
                              void* d_out, int out_size, void* d_ws, size_t ws_size,
                              hipStream_t stream) {
  (void)in_sizes; (void)n_in; (void)out_size; (void)ws_size;
  const float* input = (const float*)d_in[0];   // (8,256,64,64)
  const float* quary = (const float*)d_in[1];   // (8,3,64,64)
  const float* gnw   = (const float*)d_in[2];   // (256)
  const float* gnb   = (const float*)d_in[3];   // (256)
  const float* wq    = (const float*)d_in[4];   // (256,3)
  const float* wkv   = (const float*)d_in[5];   // (512,256)
  const float* wout  = (const float*)d_in[6];   // (256,256)
  const float* bout  = (const float*)d_in[7];   // (256)
  float* out = (float*)d_out;

  char* ws = (char*)d_ws;
  float* stats = (float*)ws;                              // 4 KB    @0
  float* wq3p  = (float*)(ws + 4096);                     // 16 KB
  float* lsum  = (float*)(ws + 20480);                    // 256 KB (2 x 32768 f32)
  float* K3x   = (float*)(ws + 282624);                   // 128 KB plane
  float* K3y   = (float*)(ws + 413696);                   // 128 KB plane
  float* K3z   = (float*)(ws + 544768);                   // 128 KB plane
  u16* w16   = (u16*)(ws + 675840);                       // 256 KB -> ends 937984
  const long base = 937984;
  u16* Vv    = (u16*)(ws + base);                         // 16 MiB (B,C,N)
  u16* Op0   = (u16*)(ws + base + 1L * 16777216);         // 16 MiB
  u16* Op1   = (u16*)(ws + base + 2L * 16777216);         // 16 MiB

  const long S = (long)NPIX * CDIM;                       // 1048576 per-batch stride

  prep<<<8, 256, 0, stream>>>(wkv, wout, wq, w16, wq3p);
  gn_stats<<<256, 1024, 0, stream>>>(input, stats);
  gn_fused<<<dim3(64, 8), 256, 0, stream>>>(input, stats, gnw, gnb, wq3p,
                                            w16, Vv, K3x, K3y, K3z);
  attn_kernel<<<dim3(32, 2, 8), 256, 0, stream>>>(quary, K3x, K3y, K3z, Vv, Op0, Op1, lsum);
  // out[o][n] = sum_c wout16[o][c] * merged(Op0,Op1)[n][c] + bout[o] + input[o][n]
  gemm_nt<true, 2><<<dim3(2, 32, 8), 256, 0, stream>>>(
      w16 + 65536, Op0, Op1, lsum, out, bout, input, 256, 4096, 0, S, S, S);
}